// Round 1
// baseline (61.161 us; speedup 1.0000x reference)
//
#include <hip/hip_runtime.h>

// Problem constants from the reference:
//   B=256, A=128, D=8, F=512 (bonds input is UNUSED by the reference)
#define B_ 256
#define A_ 128
#define D_ 8
#define F_ 512

// One block per (b, a). 128 threads, each owns one float4 (4 of 512 feats).
// Edge indices are wave-uniform per block; invalid edges (-1) load the atom's
// own row so max() is a no-op -> fully branchless inner loop.
__global__ __launch_bounds__(128) void NeuralGraphPool_kernel(
    const float* __restrict__ atoms,   // [B, A, F]
    const int*   __restrict__ edges,   // [B, A, D]
    float*       __restrict__ out)     // [B, A, F]
{
    const int blk = blockIdx.x;          // 0 .. B*A-1
    const int b   = blk >> 7;            // / A (A == 128)
    const int a   = blk & (A_ - 1);
    const int t   = threadIdx.x;         // 0 .. 127
    const int col = t * 4;

    const float* __restrict__ abase = atoms + (size_t)b * (A_ * F_);

    // 8 edge ints, contiguous: two int4 loads (uniform per block, L1-broadcast)
    const int* ep = edges + (size_t)blk * D_;
    const int4 e01 = *reinterpret_cast<const int4*>(ep);
    const int4 e23 = *reinterpret_cast<const int4*>(ep + 4);
    int e[D_] = { e01.x, e01.y, e01.z, e01.w, e23.x, e23.y, e23.z, e23.w };

    int degree = 0;
#pragma unroll
    for (int d = 0; d < D_; ++d) degree += (e[d] >= 0) ? 1 : 0;

    // Self row always participates in the max.
    float4 acc = *reinterpret_cast<const float4*>(abase + a * F_ + col);

#pragma unroll
    for (int d = 0; d < D_; ++d) {
        const int row = (e[d] >= 0) ? e[d] : a;   // invalid -> own row (identity)
        const float4 v = *reinterpret_cast<const float4*>(abase + row * F_ + col);
        acc.x = fmaxf(acc.x, v.x);
        acc.y = fmaxf(acc.y, v.y);
        acc.z = fmaxf(acc.z, v.z);
        acc.w = fmaxf(acc.w, v.w);
    }

    const float4 r = (degree != 0) ? acc : make_float4(0.f, 0.f, 0.f, 0.f);
    *reinterpret_cast<float4*>(out + (size_t)blk * F_ + col) = r;
}

extern "C" void kernel_launch(void* const* d_in, const int* in_sizes, int n_in,
                              void* d_out, int out_size, void* d_ws, size_t ws_size,
                              hipStream_t stream) {
    const float* atoms = (const float*)d_in[0];
    // d_in[1] = bonds: unused by the reference computation
    const int*   edges = (const int*)d_in[2];
    float*       out   = (float*)d_out;

    dim3 grid(B_ * A_);   // 32768 blocks
    dim3 block(128);
    hipLaunchKernelGGL(NeuralGraphPool_kernel, grid, block, 0, stream,
                       atoms, edges, out);
}

// Round 3
// 31.005 us; speedup vs baseline: 1.9726x; 1.9726x over previous
//
#include <hip/hip_runtime.h>

// Problem constants from the reference:
//   B=256, A=128, D=8, F=512 (bonds input is UNUSED by the reference)
#define B_ 256
#define A_ 128
#define D_ 8
#define F_ 512
#define NXCD 8

// Native clang vector type: usable with __builtin_nontemporal_store
// (HIP's float4 class is not).
typedef float  vfloat4 __attribute__((ext_vector_type(4)));
typedef int    vint4   __attribute__((ext_vector_type(4)));

// One block per (b, a). 128 threads, each owns one float4 (4 of 512 feats).
// XCD-aware swizzle: hardware round-robins blockIdx.x across the 8 XCDs
// (each with a private 4 MiB L2). Remap so each XCD processes a contiguous
// chunk of 4096 logical blocks = 32 whole batches -> each batch's 256 KB
// atom slab is gather-reused within ONE L2 instead of fetched by all 8.
__global__ __launch_bounds__(128) void NeuralGraphPool_kernel(
    const float* __restrict__ atoms,   // [B, A, F]
    const int*   __restrict__ edges,   // [B, A, D]
    float*       __restrict__ out)     // [B, A, F]
{
    // grid = 32768 = 8 * 4096 exactly -> simple swizzle is bijective.
    const int hw  = blockIdx.x;
    const int blk = (hw & (NXCD - 1)) * ((B_ * A_) / NXCD) + (hw >> 3);

    const int b   = blk >> 7;            // / A (A == 128)
    const int a   = blk & (A_ - 1);
    const int t   = threadIdx.x;         // 0 .. 127
    const int col = t * 4;

    const float* __restrict__ abase = atoms + (size_t)b * (A_ * F_);

    // 8 edge ints, contiguous: two int4 loads (uniform per block)
    const int* ep = edges + (size_t)blk * D_;
    const vint4 e01 = *reinterpret_cast<const vint4*>(ep);
    const vint4 e23 = *reinterpret_cast<const vint4*>(ep + 4);
    int e[D_] = { e01.x, e01.y, e01.z, e01.w, e23.x, e23.y, e23.z, e23.w };

    int degree = 0;
#pragma unroll
    for (int d = 0; d < D_; ++d) degree += (e[d] >= 0) ? 1 : 0;

    // Self row always participates in the max.
    vfloat4 acc = *reinterpret_cast<const vfloat4*>(abase + a * F_ + col);

#pragma unroll
    for (int d = 0; d < D_; ++d) {
        const int row = (e[d] >= 0) ? e[d] : a;   // invalid -> own row (identity)
        const vfloat4 v = *reinterpret_cast<const vfloat4*>(abase + row * F_ + col);
        acc.x = fmaxf(acc.x, v.x);
        acc.y = fmaxf(acc.y, v.y);
        acc.z = fmaxf(acc.z, v.z);
        acc.w = fmaxf(acc.w, v.w);
    }

    vfloat4 r = acc;
    if (degree == 0) { r = (vfloat4)(0.f); }
    // Non-temporal store: output is written once, never re-read ->
    // don't let it evict atom slabs from L2.
    __builtin_nontemporal_store(r, reinterpret_cast<vfloat4*>(out + (size_t)blk * F_ + col));
}

extern "C" void kernel_launch(void* const* d_in, const int* in_sizes, int n_in,
                              void* d_out, int out_size, void* d_ws, size_t ws_size,
                              hipStream_t stream) {
    const float* atoms = (const float*)d_in[0];
    // d_in[1] = bonds: unused by the reference computation
    const int*   edges = (const int*)d_in[2];
    float*       out   = (float*)d_out;

    dim3 grid(B_ * A_);   // 32768 blocks
    dim3 block(128);
    hipLaunchKernelGGL(NeuralGraphPool_kernel, grid, block, 0, stream,
                       atoms, edges, out);
}

// Round 4
// 25.669 us; speedup vs baseline: 2.3826x; 1.2079x over previous
//
#include <hip/hip_runtime.h>

// Problem constants from the reference:
//   B=256, A=128, D=8, F=512 (bonds input is UNUSED by the reference)
#define B_ 256
#define A_ 128
#define D_ 8
#define F_ 512
#define FC 64                 // feature-chunk (floats) handled per block
#define NCHUNK (F_ / FC)      // 8 chunks per batch
#define THREADS 256
#define NXCD 8

typedef float vfloat4 __attribute__((ext_vector_type(4)));
typedef int   vint4   __attribute__((ext_vector_type(4)));

// One block per (batch, feature-chunk). Stage the 128x64-float stripe (32 KB)
// + all 1024 edges (4 KB) in LDS; each slab byte is fetched from HBM exactly
// once, and the 9-way gather becomes LDS reads (zero L2 gather traffic).
// LDS row = 256 B covers all 32 banks uniformly -> gather is conflict-free
// regardless of which rows the (group-uniform) edge indices select.
__global__ __launch_bounds__(THREADS) void NeuralGraphPool_kernel(
    const float* __restrict__ atoms,   // [B, A, F]
    const int*   __restrict__ edges,   // [B, A, D]
    float*       __restrict__ out)     // [B, A, F]
{
    __shared__ float slab[A_ * FC];    // 32 KB, [atom][fc] row-major
    __shared__ int   eds[A_ * D_];     // 4 KB

    // XCD swizzle (grid 2048 = 8*256, bijective): the 8 chunks of one batch
    // land on one XCD -> edges fetched ~once per batch, contiguous streams.
    const int hw  = blockIdx.x;
    const int blk = (hw & (NXCD - 1)) * ((B_ * NCHUNK) / NXCD) + (hw >> 3);

    const int b   = blk >> 3;                    // / NCHUNK
    const int fc0 = (blk & (NCHUNK - 1)) * FC;
    const int t   = threadIdx.x;

    const float* __restrict__ abase = atoms + (size_t)b * (A_ * F_) + fc0;

    // --- stage edges: 1024 ints = 256 int4, one per thread ---
    {
        const vint4 ev = *reinterpret_cast<const vint4*>(
            edges + (size_t)b * (A_ * D_) + t * 4);
        *reinterpret_cast<vint4*>(eds + t * 4) = ev;
    }

    // --- stage slab: 2048 float4 over 8 iterations (coalesced 256B rows) ---
#pragma unroll
    for (int j = 0; j < (A_ * FC / 4) / THREADS; ++j) {
        const int fi = j * THREADS + t;          // flat float4 index
        const int a  = fi >> 4;                  // / (FC/4)
        const int c  = fi & 15;
        const vfloat4 v = *reinterpret_cast<const vfloat4*>(abase + a * F_ + c * 4);
        *reinterpret_cast<vfloat4*>(slab + fi * 4) = v;
    }
    __syncthreads();

    // --- compute: 2048 output float4 over 8 iterations ---
#pragma unroll 2
    for (int k = 0; k < (A_ * FC / 4) / THREADS; ++k) {
        const int o = k * THREADS + t;
        const int a = o >> 4;
        const int c = (o & 15) * 4;

        int e[D_];
        int degree = 0;
#pragma unroll
        for (int d = 0; d < D_; ++d) {
            e[d] = eds[a * D_ + d];              // broadcast within 16-lane group
            degree += (e[d] >= 0) ? 1 : 0;
        }

        vfloat4 acc = *reinterpret_cast<const vfloat4*>(slab + a * FC + c);
#pragma unroll
        for (int d = 0; d < D_; ++d) {
            const int row = (e[d] >= 0) ? e[d] : a;   // invalid -> self (identity)
            const vfloat4 v = *reinterpret_cast<const vfloat4*>(slab + row * FC + c);
            acc.x = fmaxf(acc.x, v.x);
            acc.y = fmaxf(acc.y, v.y);
            acc.z = fmaxf(acc.z, v.z);
            acc.w = fmaxf(acc.w, v.w);
        }

        vfloat4 r = acc;
        if (degree == 0) r = (vfloat4)(0.f);
        __builtin_nontemporal_store(r, reinterpret_cast<vfloat4*>(
            out + (size_t)b * (A_ * F_) + a * F_ + fc0 + c));
    }
}

extern "C" void kernel_launch(void* const* d_in, const int* in_sizes, int n_in,
                              void* d_out, int out_size, void* d_ws, size_t ws_size,
                              hipStream_t stream) {
    const float* atoms = (const float*)d_in[0];
    // d_in[1] = bonds: unused by the reference computation
    const int*   edges = (const int*)d_in[2];
    float*       out   = (float*)d_out;

    dim3 grid(B_ * NCHUNK);   // 2048 blocks
    dim3 block(THREADS);
    hipLaunchKernelGGL(NeuralGraphPool_kernel, grid, block, 0, stream,
                       atoms, edges, out);
}

// Round 5
// 25.621 us; speedup vs baseline: 2.3871x; 1.0019x over previous
//
#include <hip/hip_runtime.h>

// Problem constants from the reference:
//   B=256, A=128, D=8, F=512 (bonds input is UNUSED by the reference)
#define B_ 256
#define A_ 128
#define D_ 8
#define F_ 512
#define FC 32                 // feature-chunk (floats) per block
#define NCHUNK (F_ / FC)      // 16 chunks per batch
#define THREADS 256
#define NXCD 8

typedef float vfloat4 __attribute__((ext_vector_type(4)));

typedef __attribute__((address_space(3))) void        as3_void;
typedef const __attribute__((address_space(1))) void  as1_void;

// Direct global->LDS 16B copy (no VGPR round-trip). LDS dest must be
// wave-uniform base + lane*16 (our linear layout satisfies this); the
// GLOBAL source may be per-lane arbitrary.
__device__ __forceinline__ void gload_lds16(const void* g, void* l) {
    __builtin_amdgcn_global_load_lds((as1_void*)g, (as3_void*)l, 16, 0, 0);
}

// One block per (batch, feature-chunk). Stage the 128x32-float stripe (16 KB)
// + the batch's 1024 edges (4 KB) direct-to-LDS; each slab byte is fetched
// from HBM exactly once; the 9-way gather is pure LDS. 20 KB LDS ->
// 8 blocks/CU = 32 waves/CU (max occupancy) so staging latency of one block
// hides under the other blocks' compute/store phases.
__global__ __launch_bounds__(THREADS) void NeuralGraphPool_kernel(
    const float* __restrict__ atoms,   // [B, A, F]
    const int*   __restrict__ edges,   // [B, A, D]
    float*       __restrict__ out)     // [B, A, F]
{
    __shared__ float slab[A_ * FC];    // 16 KB, [atom][fc] row-major
    __shared__ int   eds[A_ * D_];     // 4 KB

    // XCD swizzle (grid 4096 = 8*512, bijective): one batch's 16 chunks stay
    // on one XCD -> edge re-reads are L2-local.
    const int hw  = blockIdx.x;
    const int blk = (hw & (NXCD - 1)) * ((B_ * NCHUNK) / NXCD) + (hw >> 3);

    const int b   = blk >> 4;                    // / NCHUNK (16)
    const int fc0 = (blk & (NCHUNK - 1)) * FC;
    const int t   = threadIdx.x;

    const float* __restrict__ abase = atoms + (size_t)b * (A_ * F_) + fc0;

    // --- stage edges: 1024 ints = 256 lanes x 16 B, direct-to-LDS ---
    gload_lds16(edges + (size_t)b * (A_ * D_) + t * 4, eds + t * 4);

    // --- stage slab: 1024 float4 over 4 iterations, direct-to-LDS ---
#pragma unroll
    for (int j = 0; j < (A_ * FC / 4) / THREADS; ++j) {
        const int fi = j * THREADS + t;          // flat float4 index
        const int a  = fi >> 3;                  // / (FC/4 == 8)
        const int c  = fi & 7;
        gload_lds16(abase + a * F_ + c * 4, slab + fi * 4);
    }
    __syncthreads();   // compiler drains vmcnt(0) incl. global_load_lds

    // --- compute: 1024 output float4 over 4 iterations ---
#pragma unroll
    for (int k = 0; k < (A_ * FC / 4) / THREADS; ++k) {
        const int o = k * THREADS + t;
        const int a = o >> 3;
        const int c = (o & 7) * 4;

        int e[D_];
        int degree = 0;
#pragma unroll
        for (int d = 0; d < D_; ++d) {
            e[d] = eds[a * D_ + d];              // broadcast within 8-lane group
            degree += (e[d] >= 0) ? 1 : 0;
        }

        vfloat4 acc = *reinterpret_cast<const vfloat4*>(slab + a * FC + c);
#pragma unroll
        for (int d = 0; d < D_; ++d) {
            const int row = (e[d] >= 0) ? e[d] : a;   // invalid -> self (identity)
            const vfloat4 v = *reinterpret_cast<const vfloat4*>(slab + row * FC + c);
            acc.x = fmaxf(acc.x, v.x);
            acc.y = fmaxf(acc.y, v.y);
            acc.z = fmaxf(acc.z, v.z);
            acc.w = fmaxf(acc.w, v.w);
        }

        vfloat4 r = acc;
        if (degree == 0) r = (vfloat4)(0.f);
        __builtin_nontemporal_store(r, reinterpret_cast<vfloat4*>(
            out + (size_t)b * (A_ * F_) + a * F_ + fc0 + c));
    }
}

extern "C" void kernel_launch(void* const* d_in, const int* in_sizes, int n_in,
                              void* d_out, int out_size, void* d_ws, size_t ws_size,
                              hipStream_t stream) {
    const float* atoms = (const float*)d_in[0];
    // d_in[1] = bonds: unused by the reference computation
    const int*   edges = (const int*)d_in[2];
    float*       out   = (float*)d_out;

    dim3 grid(B_ * NCHUNK);   // 4096 blocks
    dim3 block(THREADS);
    hipLaunchKernelGGL(NeuralGraphPool_kernel, grid, block, 0, stream,
                       atoms, edges, out);
}

// Round 6
// 25.282 us; speedup vs baseline: 2.4191x; 1.0134x over previous
//
#include <hip/hip_runtime.h>

// Problem constants from the reference:
//   B=256, A=128, D=8, F=512 (bonds input is UNUSED by the reference)
#define B_ 256
#define A_ 128
#define D_ 8
#define F_ 512
#define FC 32                 // feature-chunk (floats) per block
#define NCHUNK (F_ / FC)      // 16 chunks per batch
#define THREADS 256
#define NXCD 8

typedef float vfloat4 __attribute__((ext_vector_type(4)));

typedef __attribute__((address_space(3))) void        as3_void;
typedef const __attribute__((address_space(1))) void  as1_void;

// Direct global->LDS 16B copy (no VGPR round-trip). LDS dest must be
// wave-uniform base + lane*16 (our linear layout satisfies this); the
// GLOBAL source may be per-lane arbitrary.
__device__ __forceinline__ void gload_lds16(const void* g, void* l) {
    __builtin_amdgcn_global_load_lds((as1_void*)g, (as3_void*)l, 16, 0, 0);
}

// One block per (batch, feature-chunk). Stage the 128x32-float stripe (16 KB)
// + the batch's 1024 edges (4 KB) direct-to-LDS; the 9-way gather is pure
// LDS. R6 A/B: plain stores instead of non-temporal — with LDS staging there
// is no inter-block atom reuse left in L2, so the NT hint's only effect is
// (potentially) a slower write path vs L2 write-back (fill kernels sustain
// 6.9 TB/s with plain stores).
__global__ __launch_bounds__(THREADS) void NeuralGraphPool_kernel(
    const float* __restrict__ atoms,   // [B, A, F]
    const int*   __restrict__ edges,   // [B, A, D]
    float*       __restrict__ out)     // [B, A, F]
{
    __shared__ float slab[A_ * FC];    // 16 KB, [atom][fc] row-major
    __shared__ int   eds[A_ * D_];     // 4 KB

    // XCD swizzle (grid 4096 = 8*512, bijective): one batch's 16 chunks stay
    // on one XCD -> edge re-reads are L2-local.
    const int hw  = blockIdx.x;
    const int blk = (hw & (NXCD - 1)) * ((B_ * NCHUNK) / NXCD) + (hw >> 3);

    const int b   = blk >> 4;                    // / NCHUNK (16)
    const int fc0 = (blk & (NCHUNK - 1)) * FC;
    const int t   = threadIdx.x;

    const float* __restrict__ abase = atoms + (size_t)b * (A_ * F_) + fc0;

    // --- stage edges: 1024 ints = 256 lanes x 16 B, direct-to-LDS ---
    gload_lds16(edges + (size_t)b * (A_ * D_) + t * 4, eds + t * 4);

    // --- stage slab: 1024 float4 over 4 iterations, direct-to-LDS ---
#pragma unroll
    for (int j = 0; j < (A_ * FC / 4) / THREADS; ++j) {
        const int fi = j * THREADS + t;          // flat float4 index
        const int a  = fi >> 3;                  // / (FC/4 == 8)
        const int c  = fi & 7;
        gload_lds16(abase + a * F_ + c * 4, slab + fi * 4);
    }
    __syncthreads();   // compiler drains vmcnt(0) incl. global_load_lds

    // --- compute: 1024 output float4 over 4 iterations ---
#pragma unroll
    for (int k = 0; k < (A_ * FC / 4) / THREADS; ++k) {
        const int o = k * THREADS + t;
        const int a = o >> 3;
        const int c = (o & 7) * 4;

        int e[D_];
        int degree = 0;
#pragma unroll
        for (int d = 0; d < D_; ++d) {
            e[d] = eds[a * D_ + d];              // broadcast within 8-lane group
            degree += (e[d] >= 0) ? 1 : 0;
        }

        vfloat4 acc = *reinterpret_cast<const vfloat4*>(slab + a * FC + c);
#pragma unroll
        for (int d = 0; d < D_; ++d) {
            const int row = (e[d] >= 0) ? e[d] : a;   // invalid -> self (identity)
            const vfloat4 v = *reinterpret_cast<const vfloat4*>(slab + row * FC + c);
            acc.x = fmaxf(acc.x, v.x);
            acc.y = fmaxf(acc.y, v.y);
            acc.z = fmaxf(acc.z, v.z);
            acc.w = fmaxf(acc.w, v.w);
        }

        vfloat4 r = acc;
        if (degree == 0) r = (vfloat4)(0.f);
        *reinterpret_cast<vfloat4*>(
            out + (size_t)b * (A_ * F_) + a * F_ + fc0 + c) = r;
    }
}

extern "C" void kernel_launch(void* const* d_in, const int* in_sizes, int n_in,
                              void* d_out, int out_size, void* d_ws, size_t ws_size,
                              hipStream_t stream) {
    const float* atoms = (const float*)d_in[0];
    // d_in[1] = bonds: unused by the reference computation
    const int*   edges = (const int*)d_in[2];
    float*       out   = (float*)d_out;

    dim3 grid(B_ * NCHUNK);   // 4096 blocks
    dim3 block(THREADS);
    hipLaunchKernelGGL(NeuralGraphPool_kernel, grid, block, 0, stream,
                       atoms, edges, out);
}